// Round 1
// baseline (477.535 us; speedup 1.0000x reference)
//
#include <hip/hip_runtime.h>
#include <hip/hip_fp16.h>
#include <math.h>

typedef _Float16 f16;
typedef _Float16 f16x4 __attribute__((ext_vector_type(4)));
typedef _Float16 f16x8 __attribute__((ext_vector_type(8)));
typedef float f32x4 __attribute__((ext_vector_type(4)));

#define GLOAD_LDS16(g, l)                                                                  \
    __builtin_amdgcn_global_load_lds((const __attribute__((address_space(1))) void*)(g),   \
                                     (__attribute__((address_space(3))) void*)(l), 16, 0, 0)

// ---- shared MFMA compute step: 128x128 tile, BK=32, 4 waves (2x2), 4x4 frags/wave ----
__device__ __forceinline__ void mma_step(const f16* __restrict__ As, const f16* __restrict__ Bs,
                                         f32x4 acc[4][4], int wr, int wc, int l)
{
    f16x8 a[4], b[4];
    const int lr = l & 15, lk = (l >> 4) * 8;
#pragma unroll
    for (int m = 0; m < 4; m++) a[m] = *(const f16x8*)&As[(wr * 64 + m * 16 + lr) * 32 + lk];
#pragma unroll
    for (int n = 0; n < 4; n++) b[n] = *(const f16x8*)&Bs[(wc * 64 + n * 16 + lr) * 32 + lk];
#pragma unroll
    for (int m = 0; m < 4; m++)
#pragma unroll
        for (int n = 0; n < 4; n++)
            acc[m][n] = __builtin_amdgcn_mfma_f32_16x16x32_f16(a[m], b[n], acc[m][n], 0, 0, 0);
}

// C[16384,1024](f16) = X[16384,1024](f32) * W[1024,1024](f32, [n][k])^T
// blockIdx.z in {0,1,2} selects (query,Wq,q)/(key,Wk,k)/(value,Wv,v).
__global__ __launch_bounds__(256, 2) void gemm_xw_kernel(
    const float* __restrict__ X0, const float* __restrict__ X1, const float* __restrict__ X2,
    const float* __restrict__ W0, const float* __restrict__ W1, const float* __restrict__ W2,
    f16* __restrict__ O0, f16* __restrict__ O1, f16* __restrict__ O2)
{
    __shared__ f16 As[128 * 32];
    __shared__ f16 Bs[128 * 32];
    const int z = blockIdx.z;
    const float* A  = (z == 0) ? X0 : (z == 1) ? X1 : X2;
    const float* Bw = (z == 0) ? W0 : (z == 1) ? W1 : W2;
    f16* C          = (z == 0) ? O0 : (z == 1) ? O1 : O2;
    A  += (long long)blockIdx.y * 128 * 1024;
    Bw += (long long)blockIdx.x * 128 * 1024;

    const int tid = threadIdx.x;
    const int w = tid >> 6, l = tid & 63;
    const int wr = w >> 1, wc = w & 1;

    f32x4 acc[4][4];
#pragma unroll
    for (int i = 0; i < 4; i++)
#pragma unroll
        for (int j = 0; j < 4; j++) acc[i][j] = (f32x4){0.f, 0.f, 0.f, 0.f};

    for (int kt = 0; kt < 1024; kt += 32) {
        __syncthreads();
#pragma unroll
        for (int i = 0; i < 4; i++) {
            const int f = i * 256 + tid;        // float4 index within 128x32 tile
            const int row = f >> 3, c4 = (f & 7) * 4;
            float4 va = *(const float4*)(A  + (long long)row * 1024 + kt + c4);
            float4 vb = *(const float4*)(Bw + (long long)row * 1024 + kt + c4);
            *(f16x4*)&As[row * 32 + c4] = (f16x4){(f16)va.x, (f16)va.y, (f16)va.z, (f16)va.w};
            *(f16x4*)&Bs[row * 32 + c4] = (f16x4){(f16)vb.x, (f16)vb.y, (f16)vb.z, (f16)vb.w};
        }
        __syncthreads();
        mma_step(As, Bs, acc, wr, wc, l);
    }

    const int col = l & 15, ro = (l >> 4) * 4;
    const long long r0 = (long long)blockIdx.y * 128 + wr * 64;
    const int c0 = blockIdx.x * 128 + wc * 64;
#pragma unroll
    for (int m = 0; m < 4; m++)
#pragma unroll
        for (int n = 0; n < 4; n++)
#pragma unroll
            for (int i = 0; i < 4; i++)
                C[(r0 + m * 16 + ro + i) * 1024 + c0 + n * 16 + col] = (f16)acc[m][n][i];
}

// Generic batched NT GEMM, fp16 in: C[M,N] = A[M,K] * B[N,K]^T, global_load_lds staging.
template <int OUTF16>
__global__ __launch_bounds__(256, 2) void gemm_nt_kernel(
    const f16* __restrict__ Ab, const f16* __restrict__ Bb, void* __restrict__ Cb,
    int K, int lda, int ldb, int ldc,
    long long sA, long long sB, long long sC)
{
    __shared__ f16 As[128 * 32];
    __shared__ f16 Bs[128 * 32];
    const int z = blockIdx.z;
    const f16* A  = Ab + z * sA + (long long)blockIdx.y * 128 * lda;
    const f16* Bm = Bb + z * sB + (long long)blockIdx.x * 128 * ldb;

    const int tid = threadIdx.x;
    const int w = tid >> 6, l = tid & 63;
    const int wr = w >> 1, wc = w & 1;
    const int srow = l >> 2, skc = (l & 3) * 8;

    f32x4 acc[4][4];
#pragma unroll
    for (int i = 0; i < 4; i++)
#pragma unroll
        for (int j = 0; j < 4; j++) acc[i][j] = (f32x4){0.f, 0.f, 0.f, 0.f};

    for (int kt = 0; kt < K; kt += 32) {
        __syncthreads();
#pragma unroll
        for (int i = 0; i < 2; i++) {
            const int seg = w * 2 + i;          // 16 rows per segment, wave-uniform
            GLOAD_LDS16(A  + (long long)(seg * 16 + srow) * lda + kt + skc, &As[seg * 512]);
            GLOAD_LDS16(Bm + (long long)(seg * 16 + srow) * ldb + kt + skc, &Bs[seg * 512]);
        }
        __syncthreads();
        mma_step(As, Bs, acc, wr, wc, l);
    }

    const int col = l & 15, ro = (l >> 4) * 4;
    const long long r0 = (long long)blockIdx.y * 128 + wr * 64;
    const int c0 = blockIdx.x * 128 + wc * 64;
    if (OUTF16) {
        f16* C = (f16*)Cb + z * sC;
#pragma unroll
        for (int m = 0; m < 4; m++)
#pragma unroll
            for (int n = 0; n < 4; n++)
#pragma unroll
                for (int i = 0; i < 4; i++)
                    C[(r0 + m * 16 + ro + i) * ldc + c0 + n * 16 + col] = (f16)acc[m][n][i];
    } else {
        float* C = (float*)Cb + z * sC;
#pragma unroll
        for (int m = 0; m < 4; m++)
#pragma unroll
            for (int n = 0; n < 4; n++)
#pragma unroll
                for (int i = 0; i < 4; i++)
                    C[(r0 + m * 16 + ro + i) * ldc + c0 + n * 16 + col] = acc[m][n][i];
    }
}

// vT[b][o][s] = v[b][s][o], 64x64 LDS tiles.
__global__ __launch_bounds__(256) void transpose_v_kernel(const f16* __restrict__ v, f16* __restrict__ vT)
{
    __shared__ f16 tile[64][72];
    const int b = blockIdx.z;
    const int s0 = blockIdx.x * 64, o0 = blockIdx.y * 64;
    const int t = threadIdx.x;
    const int r = t >> 2, c = (t & 3) * 16;
    const f16* src = v + ((long long)b * 2048 + s0) * 1024 + o0;
    *(f16x8*)&tile[r][c]     = *(const f16x8*)(src + (long long)r * 1024 + c);
    *(f16x8*)&tile[r][c + 8] = *(const f16x8*)(src + (long long)r * 1024 + c + 8);
    __syncthreads();
    f16* dst = vT + ((long long)b * 1024 + o0) * 2048 + s0;
    f16 buf[16];
#pragma unroll
    for (int j = 0; j < 16; j++) buf[j] = tile[c + j][r];
    *(f16x8*)(dst + (long long)r * 2048 + c)     = *(f16x8*)&buf[0];
    *(f16x8*)(dst + (long long)r * 2048 + c + 8) = *(f16x8*)&buf[8];
}

__device__ __forceinline__ float wred_max(float v) {
#pragma unroll
    for (int o = 32; o > 0; o >>= 1) v = fmaxf(v, __shfl_xor(v, o));
    return v;
}
__device__ __forceinline__ float wred_sum(float v) {
#pragma unroll
    for (int o = 32; o > 0; o >>= 1) v += __shfl_xor(v, o);
    return v;
}

// In-place masked softmax over each 2048-wide score row (fp16).
__global__ __launch_bounds__(256) void softmax_kernel(f16* __restrict__ Sm, const int* __restrict__ mask)
{
    const long long row = blockIdx.x;
    const int b = (int)(row >> 11);
    f16* Srow = Sm + row * 2048;
    const int* mrow = mask + b * 2048;
    const int t = threadIdx.x;
    const int w = t >> 6, l = t & 63;

    f16x8 sv = *(const f16x8*)(Srow + t * 8);
    int4 m0 = *(const int4*)(mrow + t * 8);
    int4 m1 = *(const int4*)(mrow + t * 8 + 4);
    int mk[8] = {m0.x, m0.y, m0.z, m0.w, m1.x, m1.y, m1.z, m1.w};
    float v[8];
#pragma unroll
    for (int j = 0; j < 8; j++) v[j] = (float)sv[j];

    float mx = -INFINITY;
#pragma unroll
    for (int j = 0; j < 8; j++) if (mk[j]) mx = fmaxf(mx, v[j]);
    mx = wred_max(mx);
    __shared__ float redm[4], reds[4];
    if (l == 0) redm[w] = mx;
    __syncthreads();
    mx = fmaxf(fmaxf(redm[0], redm[1]), fmaxf(redm[2], redm[3]));

    if (mx == -INFINITY) {
        // reference: all scores == MASK_FILL -> softmax is exactly uniform
        const f16 u = (f16)(1.0f / 2048.0f);
        f16x8 pv;
#pragma unroll
        for (int j = 0; j < 8; j++) pv[j] = u;
        *(f16x8*)(Srow + t * 8) = pv;
        return;
    }

    float e[8];
    float s = 0.f;
#pragma unroll
    for (int j = 0; j < 8; j++) { e[j] = mk[j] ? expf(v[j] - mx) : 0.f; s += e[j]; }
    s = wred_sum(s);
    if (l == 0) reds[w] = s;
    __syncthreads();
    s = reds[0] + reds[1] + reds[2] + reds[3];
    const float inv = 1.0f / s;
    f16x8 pv;
#pragma unroll
    for (int j = 0; j < 8; j++) pv[j] = (f16)(e[j] * inv);
    *(f16x8*)(Srow + t * 8) = pv;
}

extern "C" void kernel_launch(void* const* d_in, const int* in_sizes, int n_in,
                              void* d_out, int out_size, void* d_ws, size_t ws_size,
                              hipStream_t stream)
{
    const float* query = (const float*)d_in[0];
    const float* keyi  = (const float*)d_in[1];
    const float* value = (const float*)d_in[2];
    const float* Wq    = (const float*)d_in[3];
    const float* Wk    = (const float*)d_in[4];
    const float* Wv    = (const float*)d_in[5];
    const int*   mask  = (const int*)d_in[6];
    float* out = (float*)d_out;

    // ws layout (fp16): q | k | vT | v ; score/prob buffer aliases v (dead after
    // transpose).  Total = 4*33.55MB + 33.55MB extra for S = 160 MiB.
    const long long SH = (long long)8 * 2048 * 1024;
    f16* qb  = (f16*)d_ws;
    f16* kb  = qb + SH;
    f16* vTb = kb + SH;
    f16* vb  = vTb + SH;
    f16* Pb  = vb;  // S/P buffer: 8*2048*2048 fp16, overlaps v + 33.55MB beyond

    // 1) q,k,v = X @ W^T  (f32 -> f16 on the fly)
    gemm_xw_kernel<<<dim3(8, 128, 3), 256, 0, stream>>>(query, keyi, value, Wq, Wk, Wv, qb, kb, vb);
    // 2) v -> vT
    transpose_v_kernel<<<dim3(32, 16, 8), 256, 0, stream>>>(vb, vTb);
    // 3) S = q @ k^T per batch
    gemm_nt_kernel<1><<<dim3(16, 16, 8), 256, 0, stream>>>(
        qb, kb, (void*)Pb, 1024, 1024, 1024, 2048,
        (long long)2048 * 1024, (long long)2048 * 1024, (long long)2048 * 2048);
    // 4) P = masked softmax(S), in place
    softmax_kernel<<<dim3(16384), 256, 0, stream>>>(Pb, mask);
    // 5) context = P @ vT^T  (f32 out)
    gemm_nt_kernel<0><<<dim3(8, 16, 8), 256, 0, stream>>>(
        Pb, vTb, (void*)out, 2048, 2048, 2048, 1024,
        (long long)2048 * 2048, (long long)1024 * 2048, (long long)2048 * 1024);
}

// Round 3
// 447.134 us; speedup vs baseline: 1.0680x; 1.0680x over previous
//
#include <hip/hip_runtime.h>
#include <hip/hip_fp16.h>
#include <math.h>

typedef _Float16 f16;
typedef _Float16 f16x4 __attribute__((ext_vector_type(4)));
typedef _Float16 f16x8 __attribute__((ext_vector_type(8)));
typedef float f32x4 __attribute__((ext_vector_type(4)));

#define GLOAD_LDS16(g, l)                                                                  \
    __builtin_amdgcn_global_load_lds((const __attribute__((address_space(1))) void*)(g),   \
                                     (__attribute__((address_space(3))) void*)(l), 16, 0, 0)

// ---- shared MFMA compute step: 128x128 tile, BK=32, 4 waves (2x2), 4x4 frags/wave ----
__device__ __forceinline__ void mma_step(const f16* __restrict__ As, const f16* __restrict__ Bs,
                                         f32x4 acc[4][4], int wr, int wc, int l)
{
    f16x8 a[4], b[4];
    const int lr = l & 15, lk = (l >> 4) * 8;
#pragma unroll
    for (int m = 0; m < 4; m++) a[m] = *(const f16x8*)&As[(wr * 64 + m * 16 + lr) * 32 + lk];
#pragma unroll
    for (int n = 0; n < 4; n++) b[n] = *(const f16x8*)&Bs[(wc * 64 + n * 16 + lr) * 32 + lk];
#pragma unroll
    for (int m = 0; m < 4; m++)
#pragma unroll
        for (int n = 0; n < 4; n++)
            acc[m][n] = __builtin_amdgcn_mfma_f32_16x16x32_f16(a[m], b[n], acc[m][n], 0, 0, 0);
}

// f32 -> f16 cast, vectorized float4 -> f16x4, grid-stride.
__global__ __launch_bounds__(256) void cast_kernel(const float* __restrict__ src,
                                                   f16* __restrict__ dst, int n4)
{
    const int stride = gridDim.x * blockDim.x;
    for (int i = blockIdx.x * blockDim.x + threadIdx.x; i < n4; i += stride) {
        float4 v = *(const float4*)(src + (long long)i * 4);
        *(f16x4*)(dst + (long long)i * 4) = (f16x4){(f16)v.x, (f16)v.y, (f16)v.z, (f16)v.w};
    }
}

// Three-source f32 -> f16 cast (for Wq/Wk/Wv), blockIdx.z selects source.
__global__ __launch_bounds__(256) void cast3_kernel(const float* __restrict__ s0,
                                                    const float* __restrict__ s1,
                                                    const float* __restrict__ s2,
                                                    f16* __restrict__ dst, int n4each)
{
    const int z = blockIdx.z;
    const float* src = (z == 0) ? s0 : (z == 1) ? s1 : s2;
    f16* d = dst + (long long)z * n4each * 4;
    const int stride = gridDim.x * blockDim.x;
    for (int i = blockIdx.x * blockDim.x + threadIdx.x; i < n4each; i += stride) {
        float4 v = *(const float4*)(src + (long long)i * 4);
        *(f16x4*)(d + (long long)i * 4) = (f16x4){(f16)v.x, (f16)v.y, (f16)v.z, (f16)v.w};
    }
}

// Batched NT GEMM, fp16 in: C[M,N] = A[M,K] * B[N,K]^T, global_load_lds staging.
// (Byte-identical to the round-1 proven kernel.)
template <int OUTF16>
__global__ __launch_bounds__(256, 2) void gemm_nt_kernel(
    const f16* __restrict__ Ab, const f16* __restrict__ Bb, void* __restrict__ Cb,
    int K, int lda, int ldb, int ldc,
    long long sA, long long sB, long long sC)
{
    __shared__ f16 As[128 * 32];
    __shared__ f16 Bs[128 * 32];
    const int z = blockIdx.z;
    const f16* A  = Ab + z * sA + (long long)blockIdx.y * 128 * lda;
    const f16* Bm = Bb + z * sB + (long long)blockIdx.x * 128 * ldb;

    const int tid = threadIdx.x;
    const int w = tid >> 6, l = tid & 63;
    const int wr = w >> 1, wc = w & 1;
    const int srow = l >> 2, skc = (l & 3) * 8;

    f32x4 acc[4][4];
#pragma unroll
    for (int i = 0; i < 4; i++)
#pragma unroll
        for (int j = 0; j < 4; j++) acc[i][j] = (f32x4){0.f, 0.f, 0.f, 0.f};

    for (int kt = 0; kt < K; kt += 32) {
        __syncthreads();
#pragma unroll
        for (int i = 0; i < 2; i++) {
            const int seg = w * 2 + i;          // 16 rows per segment, wave-uniform
            GLOAD_LDS16(A  + (long long)(seg * 16 + srow) * lda + kt + skc, &As[seg * 512]);
            GLOAD_LDS16(Bm + (long long)(seg * 16 + srow) * ldb + kt + skc, &Bs[seg * 512]);
        }
        __syncthreads();
        mma_step(As, Bs, acc, wr, wc, l);
    }

    const int col = l & 15, ro = (l >> 4) * 4;
    const long long r0 = (long long)blockIdx.y * 128 + wr * 64;
    const int c0 = blockIdx.x * 128 + wc * 64;
    if (OUTF16) {
        f16* C = (f16*)Cb + z * sC;
#pragma unroll
        for (int m = 0; m < 4; m++)
#pragma unroll
            for (int n = 0; n < 4; n++)
#pragma unroll
                for (int i = 0; i < 4; i++)
                    C[(r0 + m * 16 + ro + i) * ldc + c0 + n * 16 + col] = (f16)acc[m][n][i];
    } else {
        float* C = (float*)Cb + z * sC;
#pragma unroll
        for (int m = 0; m < 4; m++)
#pragma unroll
            for (int n = 0; n < 4; n++)
#pragma unroll
                for (int i = 0; i < 4; i++)
                    C[(r0 + m * 16 + ro + i) * ldc + c0 + n * 16 + col] = acc[m][n][i];
    }
}

// vT[b][o][s] = v[b][s][o], 64x64 LDS tiles.
__global__ __launch_bounds__(256) void transpose_v_kernel(const f16* __restrict__ v, f16* __restrict__ vT)
{
    __shared__ f16 tile[64][72];
    const int b = blockIdx.z;
    const int s0 = blockIdx.x * 64, o0 = blockIdx.y * 64;
    const int t = threadIdx.x;
    const int r = t >> 2, c = (t & 3) * 16;
    const f16* src = v + ((long long)b * 2048 + s0) * 1024 + o0;
    *(f16x8*)&tile[r][c]     = *(const f16x8*)(src + (long long)r * 1024 + c);
    *(f16x8*)&tile[r][c + 8] = *(const f16x8*)(src + (long long)r * 1024 + c + 8);
    __syncthreads();
    f16* dst = vT + ((long long)b * 1024 + o0) * 2048 + s0;
    f16 buf[16];
#pragma unroll
    for (int j = 0; j < 16; j++) buf[j] = tile[c + j][r];
    *(f16x8*)(dst + (long long)r * 2048 + c)     = *(f16x8*)&buf[0];
    *(f16x8*)(dst + (long long)r * 2048 + c + 8) = *(f16x8*)&buf[8];
}

__device__ __forceinline__ float wred_max(float v) {
#pragma unroll
    for (int o = 32; o > 0; o >>= 1) v = fmaxf(v, __shfl_xor(v, o));
    return v;
}
__device__ __forceinline__ float wred_sum(float v) {
#pragma unroll
    for (int o = 32; o > 0; o >>= 1) v += __shfl_xor(v, o);
    return v;
}

// In-place masked softmax over each 2048-wide score row (fp16).
__global__ __launch_bounds__(256) void softmax_kernel(f16* __restrict__ Sm, const int* __restrict__ mask)
{
    const long long row = blockIdx.x;
    const int b = (int)(row >> 11);
    f16* Srow = Sm + row * 2048;
    const int* mrow = mask + b * 2048;
    const int t = threadIdx.x;
    const int w = t >> 6, l = t & 63;

    f16x8 sv = *(const f16x8*)(Srow + t * 8);
    int4 m0 = *(const int4*)(mrow + t * 8);
    int4 m1 = *(const int4*)(mrow + t * 8 + 4);
    int mk[8] = {m0.x, m0.y, m0.z, m0.w, m1.x, m1.y, m1.z, m1.w};
    float v[8];
#pragma unroll
    for (int j = 0; j < 8; j++) v[j] = (float)sv[j];

    float mx = -INFINITY;
#pragma unroll
    for (int j = 0; j < 8; j++) if (mk[j]) mx = fmaxf(mx, v[j]);
    mx = wred_max(mx);
    __shared__ float redm[4], reds[4];
    if (l == 0) redm[w] = mx;
    __syncthreads();
    mx = fmaxf(fmaxf(redm[0], redm[1]), fmaxf(redm[2], redm[3]));

    if (mx == -INFINITY) {
        // reference: all scores == MASK_FILL -> softmax is exactly uniform
        const f16 u = (f16)(1.0f / 2048.0f);
        f16x8 pv;
#pragma unroll
        for (int j = 0; j < 8; j++) pv[j] = u;
        *(f16x8*)(Srow + t * 8) = pv;
        return;
    }

    float e[8];
    float s = 0.f;
#pragma unroll
    for (int j = 0; j < 8; j++) { e[j] = mk[j] ? expf(v[j] - mx) : 0.f; s += e[j]; }
    s = wred_sum(s);
    if (l == 0) reds[w] = s;
    __syncthreads();
    s = reds[0] + reds[1] + reds[2] + reds[3];
    const float inv = 1.0f / s;
    f16x8 pv;
#pragma unroll
    for (int j = 0; j < 8; j++) pv[j] = (f16)(e[j] * inv);
    *(f16x8*)(Srow + t * 8) = pv;
}

extern "C" void kernel_launch(void* const* d_in, const int* in_sizes, int n_in,
                              void* d_out, int out_size, void* d_ws, size_t ws_size,
                              hipStream_t stream)
{
    const float* query = (const float*)d_in[0];
    const float* keyi  = (const float*)d_in[1];
    const float* value = (const float*)d_in[2];
    const float* Wq    = (const float*)d_in[3];
    const float* Wk    = (const float*)d_in[4];
    const float* Wv    = (const float*)d_in[5];
    const int*   mask  = (const int*)d_in[6];
    float* out = (float*)d_out;

    // ws layout (fp16 elements), total exactly 5*SH*2B = 167.8 MB (proven footprint):
    //   [Xbuf: 0..SH) [v: SH..2SH) [q: 2SH..3SH) [k: 3SH..4SH) [vT: 4SH..5SH)
    //   wh (f16 W's, 3*1M elems) lives at the START of the vT slot (dead before
    //   transpose runs).  P aliases [0..2SH) = Xbuf+v (both dead by S-GEMM time).
    const long long SH = (long long)8 * 2048 * 1024;
    f16* Xbuf = (f16*)d_ws;
    f16* vb   = Xbuf + SH;
    f16* qb   = Xbuf + 2 * SH;
    f16* kb   = Xbuf + 3 * SH;
    f16* vTb  = Xbuf + 4 * SH;
    f16* wh   = vTb;   // 3 * 1048576 f16 = 6 MB, overwritten later by vT
    f16* Pb   = Xbuf;  // 8*2048*2048 fp16 = 2*SH

    const int n4x = (int)(SH / 4);      // float4 count per 16M-elem input
    const int n4w = 1024 * 1024 / 4;    // float4 count per W
    const long long zero = 0;

    // 0) W -> f16 (6 MB total)
    cast3_kernel<<<dim3(128, 1, 3), 256, 0, stream>>>(Wq, Wk, Wv, wh, n4w);

    // 1) per input: cast X -> f16, then proven f16 NT GEMM (both operands gload_lds)
    const float* Xs[3] = {query, keyi, value};
    f16* Os[3] = {qb, kb, vb};
    for (int z = 0; z < 3; z++) {
        cast_kernel<<<dim3(2048), 256, 0, stream>>>(Xs[z], Xbuf, n4x);
        gemm_nt_kernel<1><<<dim3(8, 128, 1), 256, 0, stream>>>(
            Xbuf, wh + (long long)z * 1024 * 1024, (void*)Os[z],
            1024, 1024, 1024, 1024, zero, zero, zero);
    }
    // 2) v -> vT (overwrites wh region; wh is dead by now)
    transpose_v_kernel<<<dim3(32, 16, 8), 256, 0, stream>>>(vb, vTb);
    // 3) S = q @ k^T per batch
    gemm_nt_kernel<1><<<dim3(16, 16, 8), 256, 0, stream>>>(
        qb, kb, (void*)Pb, 1024, 1024, 1024, 2048,
        (long long)2048 * 1024, (long long)2048 * 1024, (long long)2048 * 2048);
    // 4) P = masked softmax(S), in place
    softmax_kernel<<<dim3(16384), 256, 0, stream>>>(Pb, mask);
    // 5) context = P @ vT^T  (f32 out)
    gemm_nt_kernel<0><<<dim3(8, 16, 8), 256, 0, stream>>>(
        Pb, vTb, (void*)out, 2048, 2048, 2048, 1024,
        (long long)2048 * 2048, (long long)1024 * 2048, (long long)2048 * 1024);
}

// Round 4
// 404.993 us; speedup vs baseline: 1.1791x; 1.1041x over previous
//
#include <hip/hip_runtime.h>
#include <hip/hip_fp16.h>
#include <math.h>

typedef _Float16 f16;
typedef _Float16 f16x4 __attribute__((ext_vector_type(4)));
typedef _Float16 f16x8 __attribute__((ext_vector_type(8)));
typedef float f32x4 __attribute__((ext_vector_type(4)));

#define GLOAD_LDS16(g, l)                                                                  \
    __builtin_amdgcn_global_load_lds((const __attribute__((address_space(1))) void*)(g),   \
                                     (__attribute__((address_space(3))) void*)(l), 16, 0, 0)

// ---- shared MFMA compute step: 128x128 tile, BK=32, 4 waves (2x2), 4x4 frags/wave ----
__device__ __forceinline__ void mma_step(const f16* __restrict__ As, const f16* __restrict__ Bs,
                                         f32x4 acc[4][4], int wr, int wc, int l)
{
    f16x8 a[4], b[4];
    const int lr = l & 15, lk = (l >> 4) * 8;
#pragma unroll
    for (int m = 0; m < 4; m++) a[m] = *(const f16x8*)&As[(wr * 64 + m * 16 + lr) * 32 + lk];
#pragma unroll
    for (int n = 0; n < 4; n++) b[n] = *(const f16x8*)&Bs[(wc * 64 + n * 16 + lr) * 32 + lk];
#pragma unroll
    for (int m = 0; m < 4; m++)
#pragma unroll
        for (int n = 0; n < 4; n++)
            acc[m][n] = __builtin_amdgcn_mfma_f32_16x16x32_f16(a[m], b[n], acc[m][n], 0, 0, 0);
}

// f32 -> f16 cast, vectorized float4 -> f16x4, grid-stride.
__global__ __launch_bounds__(256) void cast_kernel(const float* __restrict__ src,
                                                   f16* __restrict__ dst, int n4)
{
    const int stride = gridDim.x * blockDim.x;
    for (int i = blockIdx.x * blockDim.x + threadIdx.x; i < n4; i += stride) {
        float4 v = *(const float4*)(src + (long long)i * 4);
        *(f16x4*)(dst + (long long)i * 4) = (f16x4){(f16)v.x, (f16)v.y, (f16)v.z, (f16)v.w};
    }
}

// Three-source f32 -> f16 cast (for Wq/Wk/Wv), blockIdx.z selects source.
__global__ __launch_bounds__(256) void cast3_kernel(const float* __restrict__ s0,
                                                    const float* __restrict__ s1,
                                                    const float* __restrict__ s2,
                                                    f16* __restrict__ dst, int n4each)
{
    const int z = blockIdx.z;
    const float* src = (z == 0) ? s0 : (z == 1) ? s1 : s2;
    f16* d = dst + (long long)z * n4each * 4;
    const int stride = gridDim.x * blockDim.x;
    for (int i = blockIdx.x * blockDim.x + threadIdx.x; i < n4each; i += stride) {
        float4 v = *(const float4*)(src + (long long)i * 4);
        *(f16x4*)(d + (long long)i * 4) = (f16x4){(f16)v.x, (f16)v.y, (f16)v.z, (f16)v.w};
    }
}

// Batched NT GEMM, fp16 in: C[M,N] = A[M,K] * B[N,K]^T.
// Double-buffered LDS (T3-minimum 2-phase), global_load_lds staging, XCD swizzle.
// Grid: dim3(nwg_xy, 1, nz); gx = column-block count; nwg_xy must be % 8 == 0.
template <int OUTF16>
__global__ __launch_bounds__(256, 4) void gemm_nt_kernel(
    const f16* __restrict__ Ab, const f16* __restrict__ Bb, void* __restrict__ Cb,
    int K, int lda, int ldb, int ldc,
    long long sA, long long sB, long long sC, int gx)
{
    __shared__ f16 As[2][128 * 32];
    __shared__ f16 Bs[2][128 * 32];

    // XCD-aware bijective swizzle (nwg % 8 == 0 guaranteed by caller).
    const int nwg = gridDim.x;
    const int swz = (blockIdx.x & 7) * (nwg >> 3) + (blockIdx.x >> 3);
    const int bx = swz % gx;
    const int by = swz / gx;

    const int z = blockIdx.z;
    const f16* A  = Ab + z * sA + (long long)by * 128 * lda;
    const f16* Bm = Bb + z * sB + (long long)bx * 128 * ldb;

    const int tid = threadIdx.x;
    const int w = tid >> 6, l = tid & 63;
    const int wr = w >> 1, wc = w & 1;
    const int srow = l >> 2, skc = (l & 3) * 8;

    // per-thread staging source bases (row = w*32 + i*16 + srow, col = skc)
    const f16* a0 = A  + (long long)(w * 32 + srow) * lda + skc;
    const f16* b0 = Bm + (long long)(w * 32 + srow) * ldb + skc;

    f32x4 acc[4][4];
#pragma unroll
    for (int i = 0; i < 4; i++)
#pragma unroll
        for (int j = 0; j < 4; j++) acc[i][j] = (f32x4){0.f, 0.f, 0.f, 0.f};

#define STAGE(c, kt)                                                              \
    do {                                                                          \
        _Pragma("unroll")                                                         \
        for (int i_ = 0; i_ < 2; i_++) {                                          \
            GLOAD_LDS16(a0 + (long long)i_ * 16 * lda + (kt), &As[c][(w * 2 + i_) * 512]); \
            GLOAD_LDS16(b0 + (long long)i_ * 16 * ldb + (kt), &Bs[c][(w * 2 + i_) * 512]); \
        }                                                                         \
    } while (0)

    const int nt = K / 32;
    STAGE(0, 0);
    asm volatile("s_waitcnt vmcnt(0)");
    __syncthreads();
    int cur = 0;
    for (int t = 0; t < nt - 1; ++t) {
        STAGE(cur ^ 1, (t + 1) * 32);      // prefetch next tile into other buffer
        mma_step(As[cur], Bs[cur], acc, wr, wc, l);
        asm volatile("s_waitcnt vmcnt(0)");
        __syncthreads();
        cur ^= 1;
    }
    mma_step(As[cur], Bs[cur], acc, wr, wc, l);
#undef STAGE

    const int col = l & 15, ro = (l >> 4) * 4;
    const long long r0 = (long long)by * 128 + wr * 64;
    const int c0 = bx * 128 + wc * 64;
    if (OUTF16) {
        f16* C = (f16*)Cb + z * sC;
#pragma unroll
        for (int m = 0; m < 4; m++)
#pragma unroll
            for (int n = 0; n < 4; n++)
#pragma unroll
                for (int i = 0; i < 4; i++)
                    C[(r0 + m * 16 + ro + i) * ldc + c0 + n * 16 + col] = (f16)acc[m][n][i];
    } else {
        float* C = (float*)Cb + z * sC;
#pragma unroll
        for (int m = 0; m < 4; m++)
#pragma unroll
            for (int n = 0; n < 4; n++)
#pragma unroll
                for (int i = 0; i < 4; i++)
                    C[(r0 + m * 16 + ro + i) * ldc + c0 + n * 16 + col] = acc[m][n][i];
    }
}

// vT[b][o][s] = v[b][s][o], 64x64 LDS tiles.
__global__ __launch_bounds__(256) void transpose_v_kernel(const f16* __restrict__ v, f16* __restrict__ vT)
{
    __shared__ f16 tile[64][72];
    const int b = blockIdx.z;
    const int s0 = blockIdx.x * 64, o0 = blockIdx.y * 64;
    const int t = threadIdx.x;
    const int r = t >> 2, c = (t & 3) * 16;
    const f16* src = v + ((long long)b * 2048 + s0) * 1024 + o0;
    *(f16x8*)&tile[r][c]     = *(const f16x8*)(src + (long long)r * 1024 + c);
    *(f16x8*)&tile[r][c + 8] = *(const f16x8*)(src + (long long)r * 1024 + c + 8);
    __syncthreads();
    f16* dst = vT + ((long long)b * 1024 + o0) * 2048 + s0;
    f16 buf[16];
#pragma unroll
    for (int j = 0; j < 16; j++) buf[j] = tile[c + j][r];
    *(f16x8*)(dst + (long long)r * 2048 + c)     = *(f16x8*)&buf[0];
    *(f16x8*)(dst + (long long)r * 2048 + c + 8) = *(f16x8*)&buf[8];
}

__device__ __forceinline__ float wred_max(float v) {
#pragma unroll
    for (int o = 32; o > 0; o >>= 1) v = fmaxf(v, __shfl_xor(v, o));
    return v;
}
__device__ __forceinline__ float wred_sum(float v) {
#pragma unroll
    for (int o = 32; o > 0; o >>= 1) v += __shfl_xor(v, o);
    return v;
}

// In-place masked softmax over each 2048-wide score row (fp16).
__global__ __launch_bounds__(256) void softmax_kernel(f16* __restrict__ Sm, const int* __restrict__ mask)
{
    const long long row = blockIdx.x;
    const int b = (int)(row >> 11);
    f16* Srow = Sm + row * 2048;
    const int* mrow = mask + b * 2048;
    const int t = threadIdx.x;
    const int w = t >> 6, l = t & 63;

    f16x8 sv = *(const f16x8*)(Srow + t * 8);
    int4 m0 = *(const int4*)(mrow + t * 8);
    int4 m1 = *(const int4*)(mrow + t * 8 + 4);
    int mk[8] = {m0.x, m0.y, m0.z, m0.w, m1.x, m1.y, m1.z, m1.w};
    float v[8];
#pragma unroll
    for (int j = 0; j < 8; j++) v[j] = (float)sv[j];

    float mx = -INFINITY;
#pragma unroll
    for (int j = 0; j < 8; j++) if (mk[j]) mx = fmaxf(mx, v[j]);
    mx = wred_max(mx);
    __shared__ float redm[4], reds[4];
    if (l == 0) redm[w] = mx;
    __syncthreads();
    mx = fmaxf(fmaxf(redm[0], redm[1]), fmaxf(redm[2], redm[3]));

    if (mx == -INFINITY) {
        // reference: all scores == MASK_FILL -> softmax is exactly uniform
        const f16 u = (f16)(1.0f / 2048.0f);
        f16x8 pv;
#pragma unroll
        for (int j = 0; j < 8; j++) pv[j] = u;
        *(f16x8*)(Srow + t * 8) = pv;
        return;
    }

    float e[8];
    float s = 0.f;
#pragma unroll
    for (int j = 0; j < 8; j++) { e[j] = mk[j] ? expf(v[j] - mx) : 0.f; s += e[j]; }
    s = wred_sum(s);
    if (l == 0) reds[w] = s;
    __syncthreads();
    s = reds[0] + reds[1] + reds[2] + reds[3];
    const float inv = 1.0f / s;
    f16x8 pv;
#pragma unroll
    for (int j = 0; j < 8; j++) pv[j] = (f16)(e[j] * inv);
    *(f16x8*)(Srow + t * 8) = pv;
}

extern "C" void kernel_launch(void* const* d_in, const int* in_sizes, int n_in,
                              void* d_out, int out_size, void* d_ws, size_t ws_size,
                              hipStream_t stream)
{
    const float* query = (const float*)d_in[0];
    const float* keyi  = (const float*)d_in[1];
    const float* value = (const float*)d_in[2];
    const float* Wq    = (const float*)d_in[3];
    const float* Wk    = (const float*)d_in[4];
    const float* Wv    = (const float*)d_in[5];
    const int*   mask  = (const int*)d_in[6];
    float* out = (float*)d_out;

    // ws layout (fp16 elements), total exactly 5*SH*2B = 167.8 MB (proven footprint):
    //   [Xbuf: 0..SH) [v: SH..2SH) [q: 2SH..3SH) [k: 3SH..4SH) [vT: 4SH..5SH)
    //   wh (f16 W's, 3*1M elems) lives at the START of the vT slot (dead before
    //   transpose runs).  P aliases [0..2SH) = Xbuf+v (both dead by S-GEMM time).
    const long long SH = (long long)8 * 2048 * 1024;
    f16* Xbuf = (f16*)d_ws;
    f16* vb   = Xbuf + SH;
    f16* qb   = Xbuf + 2 * SH;
    f16* kb   = Xbuf + 3 * SH;
    f16* vTb  = Xbuf + 4 * SH;
    f16* wh   = vTb;   // 3 * 1048576 f16 = 6 MB, overwritten later by vT
    f16* Pb   = Xbuf;  // 8*2048*2048 fp16 = 2*SH

    const int n4x = (int)(SH / 4);      // float4 count per 16M-elem input
    const int n4w = 1024 * 1024 / 4;    // float4 count per W
    const long long zero = 0;

    // 0) W -> f16 (6 MB total)
    cast3_kernel<<<dim3(128, 1, 3), 256, 0, stream>>>(Wq, Wk, Wv, wh, n4w);

    // 1) per input: cast X -> f16, then dbuf f16 NT GEMM (grid flattened, gx=8)
    const float* Xs[3] = {query, keyi, value};
    f16* Os[3] = {qb, kb, vb};
    for (int z = 0; z < 3; z++) {
        cast_kernel<<<dim3(2048), 256, 0, stream>>>(Xs[z], Xbuf, n4x);
        gemm_nt_kernel<1><<<dim3(1024, 1, 1), 256, 0, stream>>>(
            Xbuf, wh + (long long)z * 1024 * 1024, (void*)Os[z],
            1024, 1024, 1024, 1024, zero, zero, zero, 8);
    }
    // 2) v -> vT (overwrites wh region; wh is dead by now)
    transpose_v_kernel<<<dim3(32, 16, 8), 256, 0, stream>>>(vb, vTb);
    // 3) S = q @ k^T per batch  (16x16 blocks per z, gx=16)
    gemm_nt_kernel<1><<<dim3(256, 1, 8), 256, 0, stream>>>(
        qb, kb, (void*)Pb, 1024, 1024, 1024, 2048,
        (long long)2048 * 1024, (long long)2048 * 1024, (long long)2048 * 2048, 16);
    // 4) P = masked softmax(S), in place
    softmax_kernel<<<dim3(16384), 256, 0, stream>>>(Pb, mask);
    // 5) context = P @ vT^T  (f32 out; 8x16 blocks per z, gx=8)
    gemm_nt_kernel<0><<<dim3(128, 1, 8), 256, 0, stream>>>(
        Pb, vTb, (void*)out, 2048, 2048, 2048, 1024,
        (long long)2048 * 2048, (long long)1024 * 2048, (long long)2048 * 1024, 8);
}